// Round 2
// baseline (7406.005 us; speedup 1.0000x reference)
//
#include <hip/hip_runtime.h>
#include <hip/hip_bf16.h>

typedef __hip_bfloat16 bf16;
typedef __bf16 bf16x8 __attribute__((ext_vector_type(8)));
typedef __bf16 bf16x4 __attribute__((ext_vector_type(4)));
typedef float f32x4 __attribute__((ext_vector_type(4)));

#define DN_ 256
#define DE_ 64
#define DM_ 256
#define DX_ 256
#define LDA1 264   // padded LDS stride (bf16 elems) for K=256 tiles
#define LDA2 72    // padded LDS stride for K=64 tiles

static __device__ __forceinline__ float b2f(bf16 x) { return __bfloat162float(x); }
static __device__ __forceinline__ bf16 f2b(float x) { return __float2bfloat16(x); }

static __device__ __forceinline__ f32x4 mfma16(bf16x8 a, bf16x8 b, f32x4 c) {
    return __builtin_amdgcn_mfma_f32_16x16x32_bf16(a, b, c, 0, 0, 0);
}

// 64x256 output tile GEMM: acc += T(64xK in LDS, bf16) @ WT (bf16, transposed: WT[n*K+k]).
// 4 waves: wave w owns cols [64w, 64w+64); per wave: 4 mtiles x 4 ntiles of 16x16.
template <int LDA, int KTOT>
static __device__ __forceinline__ void gemm_acc(const bf16* T, const bf16* WT,
                                                f32x4 acc[4][4], int lane, int wave) {
    const int m = lane & 15, quad = lane >> 4;
#pragma unroll
    for (int k0 = 0; k0 < KTOT; k0 += 32) {
        bf16x8 a[4], b[4];
#pragma unroll
        for (int i = 0; i < 4; ++i)
            a[i] = *(const bf16x8*)&T[(i * 16 + m) * LDA + k0 + quad * 8];
#pragma unroll
        for (int j = 0; j < 4; ++j) {
            int n = wave * 64 + j * 16 + m;
            b[j] = *(const bf16x8*)&WT[(size_t)n * KTOT + k0 + quad * 8];
        }
#pragma unroll
        for (int i = 0; i < 4; ++i)
#pragma unroll
            for (int j = 0; j < 4; ++j)
                acc[i][j] = mfma16(a[i], b[j], acc[i][j]);
    }
}

// W (f32, K x NC row-major) -> WT (bf16, NC x K)
__global__ void __launch_bounds__(256) k_transpose(const float* __restrict__ W,
                                                   bf16* __restrict__ WT, int K, int NC) {
    int i = blockIdx.x * 256 + threadIdx.x;
    if (i < K * NC) {
        int k = i / NC, n = i % NC;
        WT[n * K + k] = f2b(W[i]);
    }
}

// base2[tree_tgt[r]] = tree_msg[r] @ W3   (rows unique, base2 pre-zeroed)
__global__ void __launch_bounds__(256) k_alpha(const float* __restrict__ tm,
                                               const int* __restrict__ tgt,
                                               const bf16* __restrict__ W3T,
                                               bf16* __restrict__ base2, int M) {
    __shared__ bf16 T[64 * LDA1];
    const int tile0 = blockIdx.x * 64, tid = threadIdx.x;
    for (int c = tid; c < 64 * 64; c += 256) {
        int r = c >> 6, cc = c & 63;
        int row = tile0 + r;
        if (row >= M) row = 0;
        float4 v = *(const float4*)(tm + (size_t)row * DM_ + cc * 4);
        bf16x4 b = {(__bf16)v.x, (__bf16)v.y, (__bf16)v.z, (__bf16)v.w};
        *(bf16x4*)&T[r * LDA1 + cc * 4] = b;
    }
    __syncthreads();
    const int lane = tid & 63, wave = tid >> 6;
    const int m = lane & 15, quad = lane >> 4;
    f32x4 acc[4][4];
#pragma unroll
    for (int i = 0; i < 4; ++i)
#pragma unroll
        for (int j = 0; j < 4; ++j) acc[i][j] = (f32x4){0.f, 0.f, 0.f, 0.f};
    gemm_acc<LDA1, 256>(T, W3T, acc, lane, wave);
#pragma unroll
    for (int i = 0; i < 4; ++i)
#pragma unroll
        for (int rr = 0; rr < 4; ++rr) {
            int row = tile0 + i * 16 + quad * 4 + rr;
            if (row < M) {
                size_t rb = (size_t)tgt[row] * DM_;
#pragma unroll
                for (int j = 0; j < 4; ++j) {
                    int col = wave * 64 + j * 16 + m;
                    base2[rb + col] = f2b(acc[i][j][rr]);
                }
            }
        }
}

// base2 = f_node[src] @ W1 + f_edge @ W2 + b1 + (alpha3 already in base2); msg = relu(base2)
__global__ void __launch_bounds__(256) k_base(const float* __restrict__ fnode,
                                              const float* __restrict__ fedge,
                                              const int* __restrict__ esrc,
                                              const bf16* __restrict__ W1T,
                                              const bf16* __restrict__ W2T,
                                              const float* __restrict__ b1,
                                              bf16* __restrict__ base2,
                                              bf16* __restrict__ msg, int E) {
    __shared__ bf16 T[64 * LDA1];
    const int tile0 = blockIdx.x * 64, tid = threadIdx.x;
    // stage gathered f_node[src[e]] rows (64 x 256)
    for (int c = tid; c < 64 * 64; c += 256) {
        int r = c >> 6, cc = c & 63;
        int e = tile0 + r;
        int s = esrc[e < E ? e : 0];
        float4 v = *(const float4*)(fnode + (size_t)s * DN_ + cc * 4);
        bf16x4 b = {(__bf16)v.x, (__bf16)v.y, (__bf16)v.z, (__bf16)v.w};
        *(bf16x4*)&T[r * LDA1 + cc * 4] = b;
    }
    __syncthreads();
    const int lane = tid & 63, wave = tid >> 6;
    const int m = lane & 15, quad = lane >> 4;
    f32x4 acc[4][4];
#pragma unroll
    for (int i = 0; i < 4; ++i)
#pragma unroll
        for (int j = 0; j < 4; ++j) acc[i][j] = (f32x4){0.f, 0.f, 0.f, 0.f};
    gemm_acc<LDA1, 256>(T, W1T, acc, lane, wave);
    __syncthreads();
    // stage contiguous f_edge rows (64 x 64)
    for (int c = tid; c < 64 * 16; c += 256) {
        int r = c >> 4, cc = c & 15;
        int e = tile0 + r;
        if (e >= E) e = 0;
        float4 v = *(const float4*)(fedge + (size_t)e * DE_ + cc * 4);
        bf16x4 b = {(__bf16)v.x, (__bf16)v.y, (__bf16)v.z, (__bf16)v.w};
        *(bf16x4*)&T[r * LDA2 + cc * 4] = b;
    }
    __syncthreads();
    gemm_acc<LDA2, 64>(T, W2T, acc, lane, wave);
#pragma unroll
    for (int i = 0; i < 4; ++i)
#pragma unroll
        for (int rr = 0; rr < 4; ++rr) {
            int e = tile0 + i * 16 + quad * 4 + rr;
            if (e < E) {
                size_t rb = (size_t)e * DM_;
#pragma unroll
                for (int j = 0; j < 4; ++j) {
                    int col = wave * 64 + j * 16 + m;
                    float v = acc[i][j][rr] + b1[col] + b2f(base2[rb + col]);
                    base2[rb + col] = f2b(v);
                    msg[rb + col] = f2b(fmaxf(v, 0.f));
                }
            }
        }
}

// agg[dst[e]] += msg[e]  (f32 atomics; avg in-degree ~3)
__global__ void __launch_bounds__(256) k_scatter(const bf16* __restrict__ msg,
                                                 const int* __restrict__ edst,
                                                 float* __restrict__ agg, int E) {
    long g = (long)blockIdx.x * 256 + threadIdx.x;
    int e = (int)(g >> 5);
    int cc = (int)(g & 31);
    if (e < E) {
        int d = edst[e];
        const unsigned short* mp = (const unsigned short*)(msg + (size_t)e * DM_ + cc * 8);
        uint4 mv = *(const uint4*)mp;
        unsigned int w[4] = {mv.x, mv.y, mv.z, mv.w};
        float* ap = agg + (size_t)d * DM_ + cc * 8;
#pragma unroll
        for (int q = 0; q < 4; ++q) {
            atomicAdd(ap + 2 * q, __uint_as_float(w[q] << 16));
            atomicAdd(ap + 2 * q + 1, __uint_as_float(w[q] & 0xFFFF0000u));
        }
    }
}

// msg = relu(base2 + (agg[src] - msg[rev]) @ W3), in place (rev pairs live in same tile)
__global__ void __launch_bounds__(256) k_update(const float* __restrict__ agg,
                                                const bf16* __restrict__ base2,
                                                const int* __restrict__ esrc,
                                                const bf16* __restrict__ W3T,
                                                bf16* __restrict__ msg, int E) {
    __shared__ bf16 T[64 * LDA1];
    const int tile0 = blockIdx.x * 64, tid = threadIdx.x;
    for (int c = tid; c < 64 * 64; c += 256) {
        int r = c >> 6, cc = c & 63;
        int e = tile0 + r;
        int ec = e < E ? e : 0;
        int s = esrc[ec];
        int erev = tile0 + (r ^ 1);
        if (erev >= E) erev = 0;
        float4 av = *(const float4*)(agg + (size_t)s * DM_ + cc * 4);
        ushort4 mv = *(const ushort4*)((const unsigned short*)msg + (size_t)erev * DM_ + cc * 4);
        float f0 = av.x - __uint_as_float((unsigned)mv.x << 16);
        float f1 = av.y - __uint_as_float((unsigned)mv.y << 16);
        float f2 = av.z - __uint_as_float((unsigned)mv.z << 16);
        float f3 = av.w - __uint_as_float((unsigned)mv.w << 16);
        bf16x4 b = {(__bf16)f0, (__bf16)f1, (__bf16)f2, (__bf16)f3};
        *(bf16x4*)&T[r * LDA1 + cc * 4] = b;
    }
    __syncthreads();
    const int lane = tid & 63, wave = tid >> 6;
    const int m = lane & 15, quad = lane >> 4;
    f32x4 acc[4][4];
#pragma unroll
    for (int i = 0; i < 4; ++i)
#pragma unroll
        for (int j = 0; j < 4; ++j) acc[i][j] = (f32x4){0.f, 0.f, 0.f, 0.f};
    gemm_acc<LDA1, 256>(T, W3T, acc, lane, wave);
#pragma unroll
    for (int i = 0; i < 4; ++i)
#pragma unroll
        for (int rr = 0; rr < 4; ++rr) {
            int e = tile0 + i * 16 + quad * 4 + rr;
            if (e < E) {
                size_t rb = (size_t)e * DM_;
#pragma unroll
                for (int j = 0; j < 4; ++j) {
                    int col = wave * 64 + j * 16 + m;
                    float v = acc[i][j][rr] + b2f(base2[rb + col]);
                    msg[rb + col] = f2b(fmaxf(v, 0.f));
                }
            }
        }
}

// x = relu(f_node @ W4 + agg @ W5 + b2)   (f32 output)
__global__ void __launch_bounds__(256) k_readout(const float* __restrict__ fnode,
                                                 const float* __restrict__ agg,
                                                 const bf16* __restrict__ W4T,
                                                 const bf16* __restrict__ W5T,
                                                 const float* __restrict__ b2,
                                                 float* __restrict__ out, int N) {
    __shared__ bf16 T[64 * LDA1];
    const int tile0 = blockIdx.x * 64, tid = threadIdx.x;
    for (int c = tid; c < 64 * 64; c += 256) {
        int r = c >> 6, cc = c & 63;
        int n = tile0 + r;
        if (n >= N) n = 0;
        float4 v = *(const float4*)(fnode + (size_t)n * DN_ + cc * 4);
        bf16x4 b = {(__bf16)v.x, (__bf16)v.y, (__bf16)v.z, (__bf16)v.w};
        *(bf16x4*)&T[r * LDA1 + cc * 4] = b;
    }
    __syncthreads();
    const int lane = tid & 63, wave = tid >> 6;
    const int m = lane & 15, quad = lane >> 4;
    f32x4 acc[4][4];
#pragma unroll
    for (int i = 0; i < 4; ++i)
#pragma unroll
        for (int j = 0; j < 4; ++j) acc[i][j] = (f32x4){0.f, 0.f, 0.f, 0.f};
    gemm_acc<LDA1, 256>(T, W4T, acc, lane, wave);
    __syncthreads();
    for (int c = tid; c < 64 * 64; c += 256) {
        int r = c >> 6, cc = c & 63;
        int n = tile0 + r;
        if (n >= N) n = 0;
        float4 v = *(const float4*)(agg + (size_t)n * DM_ + cc * 4);
        bf16x4 b = {(__bf16)v.x, (__bf16)v.y, (__bf16)v.z, (__bf16)v.w};
        *(bf16x4*)&T[r * LDA1 + cc * 4] = b;
    }
    __syncthreads();
    gemm_acc<LDA1, 256>(T, W5T, acc, lane, wave);
#pragma unroll
    for (int i = 0; i < 4; ++i)
#pragma unroll
        for (int rr = 0; rr < 4; ++rr) {
            int n = tile0 + i * 16 + quad * 4 + rr;
            if (n < N) {
                size_t rb = (size_t)n * DX_;
#pragma unroll
                for (int j = 0; j < 4; ++j) {
                    int col = wave * 64 + j * 16 + m;
                    out[rb + col] = fmaxf(acc[i][j][rr] + b2[col], 0.f);
                }
            }
        }
}

extern "C" void kernel_launch(void* const* d_in, const int* in_sizes, int n_in,
                              void* d_out, int out_size, void* d_ws, size_t ws_size,
                              hipStream_t stream) {
    const float* f_node   = (const float*)d_in[0];
    const float* f_edge   = (const float*)d_in[1];
    const float* tree_msg = (const float*)d_in[2];
    const float* W1 = (const float*)d_in[3];
    const float* W2 = (const float*)d_in[4];
    const float* W3 = (const float*)d_in[5];
    const float* b1 = (const float*)d_in[6];
    const float* W4 = (const float*)d_in[7];
    const float* W5 = (const float*)d_in[8];
    const float* b2 = (const float*)d_in[9];
    const int* edge_src = (const int*)d_in[10];
    const int* edge_dst = (const int*)d_in[11];
    const int* tree_tgt = (const int*)d_in[12];

    const int N = in_sizes[0] / DN_;
    const int E = in_sizes[1] / DE_;
    const int M = in_sizes[2] / DM_;

    char* ws = (char*)d_ws;
    size_t off = 0;
    bf16* base2 = (bf16*)(ws + off); off += (size_t)E * DM_ * 2;
    bf16* msg   = (bf16*)(ws + off); off += (size_t)E * DM_ * 2;
    float* agg  = (float*)(ws + off); off += (size_t)N * DM_ * 4;
    bf16* W1T = (bf16*)(ws + off); off += 256 * 256 * 2;
    bf16* W2T = (bf16*)(ws + off); off += 256 * 64 * 2;
    bf16* W3T = (bf16*)(ws + off); off += 256 * 256 * 2;
    bf16* W4T = (bf16*)(ws + off); off += 256 * 256 * 2;
    bf16* W5T = (bf16*)(ws + off); off += 256 * 256 * 2;

    k_transpose<<<(256 * 256 + 255) / 256, 256, 0, stream>>>(W1, W1T, 256, 256);
    k_transpose<<<(64 * 256 + 255) / 256, 256, 0, stream>>>(W2, W2T, 64, 256);
    k_transpose<<<(256 * 256 + 255) / 256, 256, 0, stream>>>(W3, W3T, 256, 256);
    k_transpose<<<(256 * 256 + 255) / 256, 256, 0, stream>>>(W4, W4T, 256, 256);
    k_transpose<<<(256 * 256 + 255) / 256, 256, 0, stream>>>(W5, W5T, 256, 256);

    hipMemsetAsync(base2, 0, (size_t)E * DM_ * 2, stream);
    k_alpha<<<(M + 63) / 64, 256, 0, stream>>>(tree_msg, tree_tgt, W3T, base2, M);
    k_base<<<(E + 63) / 64, 256, 0, stream>>>(f_node, f_edge, edge_src, W1T, W2T, b1,
                                              base2, msg, E);
    // ITERS=3; iteration 1 is msg=relu(base2) (msg starts at 0) -> folded into k_base
    for (int it = 0; it < 2; ++it) {
        hipMemsetAsync(agg, 0, (size_t)N * DM_ * 4, stream);
        k_scatter<<<(E * 32 + 255) / 256, 256, 0, stream>>>(msg, edge_dst, agg, E);
        k_update<<<(E + 63) / 64, 256, 0, stream>>>(agg, base2, edge_src, W3T, msg, E);
    }
    hipMemsetAsync(agg, 0, (size_t)N * DM_ * 4, stream);
    k_scatter<<<(E * 32 + 255) / 256, 256, 0, stream>>>(msg, edge_dst, agg, E);
    k_readout<<<(N + 63) / 64, 256, 0, stream>>>(f_node, agg, W4T, W5T, b2,
                                                 (float*)d_out, N);
}

// Round 4
// 1375.918 us; speedup vs baseline: 5.3826x; 5.3826x over previous
//
#include <hip/hip_runtime.h>
#include <hip/hip_bf16.h>

typedef __hip_bfloat16 bf16;
typedef __bf16 bf16x8 __attribute__((ext_vector_type(8)));
typedef __bf16 bf16x4 __attribute__((ext_vector_type(4)));
typedef float f32x4 __attribute__((ext_vector_type(4)));

#define DN_ 256
#define DE_ 64
#define DM_ 256
#define DX_ 256
#define LDA1 264   // padded LDS stride (bf16 elems) for K=256 tiles
#define LDA2 72    // padded LDS stride for K=64 tiles
#define CAP 32     // incoming-edge bucket capacity (Poisson mean 3; P(deg>32) ~ 1e-24)

// workspace budget: base2 153.6 + msg 153.6 + agg(bf16) 51.2 + cnt 0.4 + slot 12.8
//                   + weights 0.46 = 372.4 MB  (< 410.5 MB known-good from R2)

static __device__ __forceinline__ float b2f(bf16 x) { return __bfloat162float(x); }
static __device__ __forceinline__ bf16 f2b(float x) { return __float2bfloat16(x); }
static __device__ __forceinline__ float us2f(unsigned short u) {
    return __uint_as_float((unsigned)u << 16);
}

static __device__ __forceinline__ f32x4 mfma16(bf16x8 a, bf16x8 b, f32x4 c) {
    return __builtin_amdgcn_mfma_f32_16x16x32_bf16(a, b, c, 0, 0, 0);
}

// 64x256 output tile GEMM: acc += T(64xK in LDS, bf16) @ WT (bf16, transposed: WT[n*K+k]).
// 4 waves: wave w owns cols [64w, 64w+64); per wave: 4 mtiles x 4 ntiles of 16x16.
template <int LDA, int KTOT>
static __device__ __forceinline__ void gemm_acc(const bf16* T, const bf16* WT,
                                                f32x4 acc[4][4], int lane, int wave) {
    const int m = lane & 15, quad = lane >> 4;
#pragma unroll
    for (int k0 = 0; k0 < KTOT; k0 += 32) {
        bf16x8 a[4], b[4];
#pragma unroll
        for (int i = 0; i < 4; ++i)
            a[i] = *(const bf16x8*)&T[(i * 16 + m) * LDA + k0 + quad * 8];
#pragma unroll
        for (int j = 0; j < 4; ++j) {
            int n = wave * 64 + j * 16 + m;
            b[j] = *(const bf16x8*)&WT[(size_t)n * KTOT + k0 + quad * 8];
        }
#pragma unroll
        for (int i = 0; i < 4; ++i)
#pragma unroll
            for (int j = 0; j < 4; ++j)
                acc[i][j] = mfma16(a[i], b[j], acc[i][j]);
    }
}

// W (f32, K x NC row-major) -> WT (bf16, NC x K)
__global__ void __launch_bounds__(256) k_transpose(const float* __restrict__ W,
                                                   bf16* __restrict__ WT, int K, int NC) {
    int i = blockIdx.x * 256 + threadIdx.x;
    if (i < K * NC) {
        int k = i / NC, n = i % NC;
        WT[n * K + k] = f2b(W[i]);
    }
}

// incoming-edge buckets: slot[d*CAP + pos] = e for each e with edst[e]==d
__global__ void __launch_bounds__(256) k_bucket(const int* __restrict__ edst,
                                                int* __restrict__ cnt,
                                                int* __restrict__ slot, int E) {
    int e = blockIdx.x * 256 + threadIdx.x;
    if (e < E) {
        int d = edst[e];
        int pos = atomicAdd(&cnt[d], 1);
        if (pos < CAP) slot[(size_t)d * CAP + pos] = e;
    }
}

// agg[n] = sum over incoming edges of msg rows (f32 accumulate, bf16 store).
// One wave per node; lane covers 4 cols.
__global__ void __launch_bounds__(256) k_aggregate(const bf16* __restrict__ msg,
                                                   const int* __restrict__ cnt,
                                                   const int* __restrict__ slot,
                                                   bf16* __restrict__ agg, int N) {
    int wid = (blockIdx.x * 256 + threadIdx.x) >> 6;  // node id
    int lane = threadIdx.x & 63;
    if (wid >= N) return;
    int c = cnt[wid];
    if (c > CAP) c = CAP;
    const int* sp = slot + (size_t)wid * CAP;
    float a0 = 0.f, a1 = 0.f, a2 = 0.f, a3 = 0.f;
    for (int i = 0; i < c; ++i) {
        int e = sp[i];
        ushort4 mv = *(const ushort4*)((const unsigned short*)msg + (size_t)e * DM_ + lane * 4);
        a0 += us2f(mv.x); a1 += us2f(mv.y); a2 += us2f(mv.z); a3 += us2f(mv.w);
    }
    bf16x4 o = {(__bf16)a0, (__bf16)a1, (__bf16)a2, (__bf16)a3};
    *(bf16x4*)(agg + (size_t)wid * DM_ + lane * 4) = o;
}

// base2[tree_tgt[r]] = tree_msg[r] @ W3   (rows unique, base2 pre-zeroed)
__global__ void __launch_bounds__(256) k_alpha(const float* __restrict__ tm,
                                               const int* __restrict__ tgt,
                                               const bf16* __restrict__ W3T,
                                               bf16* __restrict__ base2, int M) {
    __shared__ bf16 T[64 * LDA1];
    const int tile0 = blockIdx.x * 64, tid = threadIdx.x;
    for (int c = tid; c < 64 * 64; c += 256) {
        int r = c >> 6, cc = c & 63;
        int row = tile0 + r;
        if (row >= M) row = 0;
        float4 v = *(const float4*)(tm + (size_t)row * DM_ + cc * 4);
        bf16x4 b = {(__bf16)v.x, (__bf16)v.y, (__bf16)v.z, (__bf16)v.w};
        *(bf16x4*)&T[r * LDA1 + cc * 4] = b;
    }
    __syncthreads();
    const int lane = tid & 63, wave = tid >> 6;
    const int m = lane & 15, quad = lane >> 4;
    f32x4 acc[4][4];
#pragma unroll
    for (int i = 0; i < 4; ++i)
#pragma unroll
        for (int j = 0; j < 4; ++j) acc[i][j] = (f32x4){0.f, 0.f, 0.f, 0.f};
    gemm_acc<LDA1, 256>(T, W3T, acc, lane, wave);
#pragma unroll
    for (int i = 0; i < 4; ++i)
#pragma unroll
        for (int rr = 0; rr < 4; ++rr) {
            int row = tile0 + i * 16 + quad * 4 + rr;
            if (row < M) {
                size_t rb = (size_t)tgt[row] * DM_;
#pragma unroll
                for (int j = 0; j < 4; ++j) {
                    int col = wave * 64 + j * 16 + m;
                    base2[rb + col] = f2b(acc[i][j][rr]);
                }
            }
        }
}

// base2 = f_node[src] @ W1 + f_edge @ W2 + b1 + (alpha3 already in base2); msg = relu(base2)
__global__ void __launch_bounds__(256) k_base(const float* __restrict__ fnode,
                                              const float* __restrict__ fedge,
                                              const int* __restrict__ esrc,
                                              const bf16* __restrict__ W1T,
                                              const bf16* __restrict__ W2T,
                                              const float* __restrict__ b1,
                                              bf16* __restrict__ base2,
                                              bf16* __restrict__ msg, int E) {
    __shared__ bf16 T[64 * LDA1];
    const int tile0 = blockIdx.x * 64, tid = threadIdx.x;
    // stage gathered f_node[src[e]] rows (64 x 256)
    for (int c = tid; c < 64 * 64; c += 256) {
        int r = c >> 6, cc = c & 63;
        int e = tile0 + r;
        int s = esrc[e < E ? e : 0];
        float4 v = *(const float4*)(fnode + (size_t)s * DN_ + cc * 4);
        bf16x4 b = {(__bf16)v.x, (__bf16)v.y, (__bf16)v.z, (__bf16)v.w};
        *(bf16x4*)&T[r * LDA1 + cc * 4] = b;
    }
    __syncthreads();
    const int lane = tid & 63, wave = tid >> 6;
    const int m = lane & 15, quad = lane >> 4;
    f32x4 acc[4][4];
#pragma unroll
    for (int i = 0; i < 4; ++i)
#pragma unroll
        for (int j = 0; j < 4; ++j) acc[i][j] = (f32x4){0.f, 0.f, 0.f, 0.f};
    gemm_acc<LDA1, 256>(T, W1T, acc, lane, wave);
    __syncthreads();
    // stage contiguous f_edge rows (64 x 64)
    for (int c = tid; c < 64 * 16; c += 256) {
        int r = c >> 4, cc = c & 15;
        int e = tile0 + r;
        if (e >= E) e = 0;
        float4 v = *(const float4*)(fedge + (size_t)e * DE_ + cc * 4);
        bf16x4 b = {(__bf16)v.x, (__bf16)v.y, (__bf16)v.z, (__bf16)v.w};
        *(bf16x4*)&T[r * LDA2 + cc * 4] = b;
    }
    __syncthreads();
    gemm_acc<LDA2, 64>(T, W2T, acc, lane, wave);
#pragma unroll
    for (int i = 0; i < 4; ++i)
#pragma unroll
        for (int rr = 0; rr < 4; ++rr) {
            int e = tile0 + i * 16 + quad * 4 + rr;
            if (e < E) {
                size_t rb = (size_t)e * DM_;
#pragma unroll
                for (int j = 0; j < 4; ++j) {
                    int col = wave * 64 + j * 16 + m;
                    float v = acc[i][j][rr] + b1[col] + b2f(base2[rb + col]);
                    base2[rb + col] = f2b(v);
                    msg[rb + col] = f2b(fmaxf(v, 0.f));
                }
            }
        }
}

// msg = relu(base2 + (agg[src] - msg[rev]) @ W3), in place (rev pairs live in same tile)
__global__ void __launch_bounds__(256) k_update(const bf16* __restrict__ agg,
                                                const bf16* __restrict__ base2,
                                                const int* __restrict__ esrc,
                                                const bf16* __restrict__ W3T,
                                                bf16* __restrict__ msg, int E) {
    __shared__ bf16 T[64 * LDA1];
    const int tile0 = blockIdx.x * 64, tid = threadIdx.x;
    for (int c = tid; c < 64 * 64; c += 256) {
        int r = c >> 6, cc = c & 63;
        int e = tile0 + r;
        int ec = e < E ? e : 0;
        int s = esrc[ec];
        int erev = tile0 + (r ^ 1);
        if (erev >= E) erev = 0;
        ushort4 av = *(const ushort4*)((const unsigned short*)agg + (size_t)s * DM_ + cc * 4);
        ushort4 mv = *(const ushort4*)((const unsigned short*)msg + (size_t)erev * DM_ + cc * 4);
        float f0 = us2f(av.x) - us2f(mv.x);
        float f1 = us2f(av.y) - us2f(mv.y);
        float f2 = us2f(av.z) - us2f(mv.z);
        float f3 = us2f(av.w) - us2f(mv.w);
        bf16x4 b = {(__bf16)f0, (__bf16)f1, (__bf16)f2, (__bf16)f3};
        *(bf16x4*)&T[r * LDA1 + cc * 4] = b;
    }
    __syncthreads();
    const int lane = tid & 63, wave = tid >> 6;
    const int m = lane & 15, quad = lane >> 4;
    f32x4 acc[4][4];
#pragma unroll
    for (int i = 0; i < 4; ++i)
#pragma unroll
        for (int j = 0; j < 4; ++j) acc[i][j] = (f32x4){0.f, 0.f, 0.f, 0.f};
    gemm_acc<LDA1, 256>(T, W3T, acc, lane, wave);
#pragma unroll
    for (int i = 0; i < 4; ++i)
#pragma unroll
        for (int rr = 0; rr < 4; ++rr) {
            int e = tile0 + i * 16 + quad * 4 + rr;
            if (e < E) {
                size_t rb = (size_t)e * DM_;
#pragma unroll
                for (int j = 0; j < 4; ++j) {
                    int col = wave * 64 + j * 16 + m;
                    float v = acc[i][j][rr] + b2f(base2[rb + col]);
                    msg[rb + col] = f2b(fmaxf(v, 0.f));
                }
            }
        }
}

// x = relu(f_node @ W4 + agg @ W5 + b2)   (f32 output)
__global__ void __launch_bounds__(256) k_readout(const float* __restrict__ fnode,
                                                 const bf16* __restrict__ agg,
                                                 const bf16* __restrict__ W4T,
                                                 const bf16* __restrict__ W5T,
                                                 const float* __restrict__ b2,
                                                 float* __restrict__ out, int N) {
    __shared__ bf16 T[64 * LDA1];
    const int tile0 = blockIdx.x * 64, tid = threadIdx.x;
    for (int c = tid; c < 64 * 64; c += 256) {
        int r = c >> 6, cc = c & 63;
        int n = tile0 + r;
        if (n >= N) n = 0;
        float4 v = *(const float4*)(fnode + (size_t)n * DN_ + cc * 4);
        bf16x4 b = {(__bf16)v.x, (__bf16)v.y, (__bf16)v.z, (__bf16)v.w};
        *(bf16x4*)&T[r * LDA1 + cc * 4] = b;
    }
    __syncthreads();
    const int lane = tid & 63, wave = tid >> 6;
    const int m = lane & 15, quad = lane >> 4;
    f32x4 acc[4][4];
#pragma unroll
    for (int i = 0; i < 4; ++i)
#pragma unroll
        for (int j = 0; j < 4; ++j) acc[i][j] = (f32x4){0.f, 0.f, 0.f, 0.f};
    gemm_acc<LDA1, 256>(T, W4T, acc, lane, wave);
    __syncthreads();
    // stage agg rows (already bf16): 64 rows x 32 uint4
    for (int c = tid; c < 64 * 32; c += 256) {
        int r = c >> 5, cc = c & 31;
        int n = tile0 + r;
        if (n >= N) n = 0;
        *(uint4*)&T[r * LDA1 + cc * 8] =
            *(const uint4*)((const unsigned short*)agg + (size_t)n * DM_ + cc * 8);
    }
    __syncthreads();
    gemm_acc<LDA1, 256>(T, W5T, acc, lane, wave);
#pragma unroll
    for (int i = 0; i < 4; ++i)
#pragma unroll
        for (int rr = 0; rr < 4; ++rr) {
            int n = tile0 + i * 16 + quad * 4 + rr;
            if (n < N) {
                size_t rb = (size_t)n * DX_;
#pragma unroll
                for (int j = 0; j < 4; ++j) {
                    int col = wave * 64 + j * 16 + m;
                    out[rb + col] = fmaxf(acc[i][j][rr] + b2[col], 0.f);
                }
            }
        }
}

extern "C" void kernel_launch(void* const* d_in, const int* in_sizes, int n_in,
                              void* d_out, int out_size, void* d_ws, size_t ws_size,
                              hipStream_t stream) {
    const float* f_node   = (const float*)d_in[0];
    const float* f_edge   = (const float*)d_in[1];
    const float* tree_msg = (const float*)d_in[2];
    const float* W1 = (const float*)d_in[3];
    const float* W2 = (const float*)d_in[4];
    const float* W3 = (const float*)d_in[5];
    const float* b1 = (const float*)d_in[6];
    const float* W4 = (const float*)d_in[7];
    const float* W5 = (const float*)d_in[8];
    const float* b2 = (const float*)d_in[9];
    const int* edge_src = (const int*)d_in[10];
    const int* edge_dst = (const int*)d_in[11];
    const int* tree_tgt = (const int*)d_in[12];

    const int N = in_sizes[0] / DN_;
    const int E = in_sizes[1] / DE_;
    const int M = in_sizes[2] / DM_;

    char* ws = (char*)d_ws;
    size_t off = 0;
    bf16* base2 = (bf16*)(ws + off); off += (size_t)E * DM_ * 2;
    bf16* msg   = (bf16*)(ws + off); off += (size_t)E * DM_ * 2;
    bf16* agg   = (bf16*)(ws + off); off += (size_t)N * DM_ * 2;
    int* cnt    = (int*)(ws + off);   off += (size_t)N * 4;
    int* slot   = (int*)(ws + off);   off += (size_t)N * CAP * 4;
    bf16* W1T = (bf16*)(ws + off); off += 256 * 256 * 2;
    bf16* W2T = (bf16*)(ws + off); off += 256 * 64 * 2;
    bf16* W3T = (bf16*)(ws + off); off += 256 * 256 * 2;
    bf16* W4T = (bf16*)(ws + off); off += 256 * 256 * 2;
    bf16* W5T = (bf16*)(ws + off); off += 256 * 256 * 2;

    k_transpose<<<(256 * 256 + 255) / 256, 256, 0, stream>>>(W1, W1T, 256, 256);
    k_transpose<<<(64 * 256 + 255) / 256, 256, 0, stream>>>(W2, W2T, 64, 256);
    k_transpose<<<(256 * 256 + 255) / 256, 256, 0, stream>>>(W3, W3T, 256, 256);
    k_transpose<<<(256 * 256 + 255) / 256, 256, 0, stream>>>(W4, W4T, 256, 256);
    k_transpose<<<(256 * 256 + 255) / 256, 256, 0, stream>>>(W5, W5T, 256, 256);

    // one-time CSR-bucket build for the (static) incoming-edge lists
    hipMemsetAsync(cnt, 0, (size_t)N * 4, stream);
    k_bucket<<<(E + 255) / 256, 256, 0, stream>>>(edge_dst, cnt, slot, E);

    hipMemsetAsync(base2, 0, (size_t)E * DM_ * 2, stream);
    k_alpha<<<(M + 63) / 64, 256, 0, stream>>>(tree_msg, tree_tgt, W3T, base2, M);
    k_base<<<(E + 63) / 64, 256, 0, stream>>>(f_node, f_edge, edge_src, W1T, W2T, b1,
                                              base2, msg, E);
    // ITERS=3; iteration 1 is msg=relu(base2) (msg starts at 0) -> folded into k_base
    for (int it = 0; it < 2; ++it) {
        k_aggregate<<<(N + 3) / 4, 256, 0, stream>>>(msg, cnt, slot, agg, N);
        k_update<<<(E + 63) / 64, 256, 0, stream>>>(agg, base2, edge_src, W3T, msg, E);
    }
    k_aggregate<<<(N + 3) / 4, 256, 0, stream>>>(msg, cnt, slot, agg, N);
    k_readout<<<(N + 63) / 64, 256, 0, stream>>>(f_node, agg, W4T, W5T, b2,
                                                 (float*)d_out, N);
}